// Round 9
// baseline (17797.606 us; speedup 1.0000x reference)
//
#include <hip/hip_runtime.h>

// ESN forward, teacher-forced: s[t] = tanh(w@s[t-1] + w_in@in[t] + w_fb@out[t-1]) + 1e-3*(nu[t]-0.5)
// Persistent kernel, 256 blocks x 256 threads, 8 rows/block, W in LDS (64KB).
//
// Round-9: R5 base + PRODUCER-ALIGNED ownership. Evidence: R8 proved extra
// fabric legs cost ~+1900cy/step (ack+read legs) while op-count reduction
// 250x bought nothing => R5's tag-fused one-way store->poll is leg-optimal;
// the residual stall is detect STRUCTURE. Change: thread tid owns cols
// 8*tid..8*tid+7 = exactly the 64B line block tid publishes. Each thread
// waits on ONE producer (all-or-nothing line detect, published by a single
// 8-lane wave store) instead of max-of-8; producer skew is absorbed across
// threads (fast threads FMA while straggler threads wait) and paid once at
// the reduce barrier. Side effect: per-line pollers 2048 -> 256.
//
// Kept from R5 (8.09ms best): W in LDS [rr][i][tid][j] 16B-lane-stride
// (0 bank conflicts), pre-poll ds_read prefetch + asm fence (lgkm rides out
// the poll's vmcnt), {fp32,tag} fused 8B agent-scope words double-buffered
// by parity, one barrier/step, wave-0 finalize + single-line publish,
// fast tanh (exp2+rcp), s_sleep(1) pacing (skipped on first retry).

#define N_RES   2048
#define N_IN    64
#define N_OUT   32
#define T_STEPS 4096
#define NOISEC  0.001f
#define NBLK    256
#define NTHR    256
#define RPB     8     // rows per block
#define CPT     8     // state words per thread: cols 8*tid .. 8*tid+7

typedef float f32x4 __attribute__((ext_vector_type(4)));

__device__ __forceinline__ float fast_tanh(float x) {
    const float e = __builtin_amdgcn_exp2f(2.8853900818f * x);
    return fmaf(-2.f, __builtin_amdgcn_rcpf(e + 1.f), 1.f);
}

__global__ void esn_init(unsigned long long* __restrict__ slots) {
    const int i = blockIdx.x * blockDim.x + threadIdx.x;
    if (i < 2 * N_RES)
        __hip_atomic_store(slots + i, 0ull, __ATOMIC_RELAXED, __HIP_MEMORY_SCOPE_AGENT);
}

__global__ __launch_bounds__(NTHR, 1)
void esn_run(const float* __restrict__ inputs,    // T x 64
             const float* __restrict__ outputs,   // T x 32
             const float* __restrict__ w,         // 2048 x 2048
             const float* __restrict__ w_in,      // 2048 x 64
             const float* __restrict__ w_feedb,   // 2048 x 32
             const float* __restrict__ out_w,     // 32 x 2048
             const float* __restrict__ out_b,     // 32
             const float* __restrict__ noise_u,   // T x 2048
             float* __restrict__ d_out,           // 32 + 2048
             unsigned long long* __restrict__ slots) { // 2 x 2048 tagged words
    const int tid  = threadIdx.x;
    const int blk  = blockIdx.x;
    const int row0 = blk * RPB;
    const int wav  = tid >> 6;
    const int lan  = tid & 63;

    // [rr][i][tid][j]: element (row = rr*4+j, col = 8*tid+i). 64KB.
    // Per-step read: thread tid -> 16 x ds_read_b128, lane stride 16B
    // (2-way bank aliasing = free). Identical addressing to R5; only the
    // global-side column mapping changed (one-time staging is uncoalesced).
    __shared__ float wlds[2 * 8 * NTHR * 4];
    __shared__ float red[2][4][RPB];

    // ---- one-time: stage W (8 rows x cols 8*tid..8*tid+7 per thread) ----
    #pragma unroll
    for (int r = 0; r < RPB; ++r)
        #pragma unroll
        for (int i = 0; i < CPT; ++i) {
            const float v = w[(size_t)(row0 + r) * N_RES + 8 * tid + i];
            wlds[(((r >> 2) * 8 + i) * NTHR + tid) * 4 + (r & 3)] = v;
        }
    // w_in / w_feedb: one virtual column per thread (tid<96)
    float wex[RPB];
    #pragma unroll
    for (int r = 0; r < RPB; ++r) {
        float v = 0.f;
        if (tid < N_IN)              v = w_in[(row0 + r) * N_IN + tid];
        else if (tid < N_IN + N_OUT) v = w_feedb[(row0 + r) * N_OUT + (tid - N_IN)];
        wex[r] = v;
    }
    __syncthreads();

    for (int t = 1; t < T_STEPS; ++t) {
        const unsigned need = (unsigned)(t - 1);
        // my single 64B line: the output of producer block `tid`
        const unsigned long long* sl =
            slots + (size_t)((t - 1) & 1) * N_RES + tid * CPT;

        // ---- issue poll sweep 0 immediately (earliest vmcnt start) ----
        unsigned long long vv[CPT];
        #pragma unroll
        for (int i = 0; i < CPT; ++i)
            vv[i] = __hip_atomic_load(sl + i, __ATOMIC_RELAXED, __HIP_MEMORY_SCOPE_AGENT);

        // off-critical-path operands (overlap with poll latency)
        float xv = 0.f;
        if (tid < N_IN)              xv = inputs[t * N_IN + tid];
        else if (tid < N_IN + N_OUT) xv = outputs[(t - 1) * N_OUT + (tid - N_IN)];
        float nu = 0.f;
        if (tid < RPB) nu = noise_u[(size_t)t * N_RES + row0 + tid];

        // ---- prefetch W fragment from LDS (state-independent) ----
        f32x4 wv[16];
        #pragma unroll
        for (int rr = 0; rr < 2; ++rr)
            #pragma unroll
            for (int i = 0; i < CPT; ++i)
                wv[rr * 8 + i] = *reinterpret_cast<const f32x4*>(
                    &wlds[((rr * 8 + i) * NTHR + tid) * 4]);

        // fence: nothing above may sink below (ds_reads ride out the poll on
        // the independent lgkmcnt counter)
        asm volatile("" ::: "memory");

        // ---- all-or-nothing detect of MY producer's line ----
        int tries = 0;
        for (;;) {
            unsigned mn = 0xffffffffu;
            #pragma unroll
            for (int i = 0; i < CPT; ++i) {
                const unsigned tg = (unsigned)(vv[i] >> 32);
                mn = (tg < mn) ? tg : mn;
            }
            if (mn >= need) break;
            if (++tries > 1) __builtin_amdgcn_s_sleep(1);
            #pragma unroll
            for (int i = 0; i < CPT; ++i)
                vv[i] = __hip_atomic_load(sl + i, __ATOMIC_RELAXED, __HIP_MEMORY_SCOPE_AGENT);
        }

        // ---- partial dots: 8 rows x my 8 contiguous cols ----
        float acc[RPB];
        #pragma unroll
        for (int r = 0; r < RPB; ++r) acc[r] = 0.f;
        #pragma unroll
        for (int i = 0; i < CPT; ++i) {
            const float sv = __uint_as_float((unsigned)(vv[i] & 0xffffffffu));
            #pragma unroll
            for (int rr = 0; rr < 2; ++rr)
                #pragma unroll
                for (int j = 0; j < 4; ++j)
                    acc[rr * 4 + j] = fmaf(wv[rr * 8 + i][j], sv, acc[rr * 4 + j]);
        }
        #pragma unroll
        for (int r = 0; r < RPB; ++r) acc[r] = fmaf(wex[r], xv, acc[r]);

        // ---- wave reduce: halving exchange (1,2,4) then butterfly (8,16,32) ----
        {   const bool s = (lan & 1);
            #pragma unroll
            for (int r = 0; r < 4; ++r) {
                const float send = s ? acc[r] : acc[r + 4];
                const float got  = __shfl_xor(send, 1, 64);
                acc[r] = (s ? acc[r + 4] : acc[r]) + got;
            }
        }
        {   const bool s = (lan >> 1) & 1;
            #pragma unroll
            for (int r = 0; r < 2; ++r) {
                const float send = s ? acc[r] : acc[r + 2];
                const float got  = __shfl_xor(send, 2, 64);
                acc[r] = (s ? acc[r + 2] : acc[r]) + got;
            }
        }
        {   const bool s = (lan >> 2) & 1;
            const float send = s ? acc[0] : acc[1];
            const float got  = __shfl_xor(send, 4, 64);
            acc[0] = (s ? acc[1] : acc[0]) + got;
        }
        #pragma unroll
        for (int m = 8; m < 64; m <<= 1) acc[0] += __shfl_xor(acc[0], m, 64);
        if (lan < 8) {
            const int rb = 4 * (lan & 1) + 2 * ((lan >> 1) & 1) + ((lan >> 2) & 1);
            red[t & 1][wav][rb] = acc[0];
        }
        __syncthreads();

        // ---- wave 0, lanes 0-7: final sum + tanh + single-line publish ----
        if (tid < RPB) {
            const float tot = red[t & 1][0][tid] + red[t & 1][1][tid]
                            + red[t & 1][2][tid] + red[t & 1][3][tid];
            const float val = fast_tanh(tot) + NOISEC * (nu - 0.5f);
            const unsigned long long pk =
                ((unsigned long long)(unsigned)t << 32) |
                (unsigned long long)__float_as_uint(val);
            __hip_atomic_store(slots + (size_t)(t & 1) * N_RES + row0 + tid, pk,
                               __ATOMIC_RELAXED, __HIP_MEMORY_SCOPE_AGENT);
            if (t == T_STEPS - 1) d_out[32 + row0 + tid] = val;
        }
        // no second barrier: red[] double-buffered by t&1; the next write to
        // this parity is behind the t+1 barrier, after wave0's read.
    }

    // ---- epilogue: block 0 computes readout = out_w @ s_final + out_b ----
    if (blk == 0) {
        const unsigned long long* sf = slots + (size_t)((T_STEPS - 1) & 1) * N_RES;
        const int r2 = tid >> 3, j2 = tid & 7;     // 32 rows x 8 lanes
        const unsigned need = (unsigned)(T_STEPS - 1);
        float acc = 0.f;
        for (int c0 = 0; c0 < N_RES / 8; c0 += 8) { // 256 cols/lane, 8 at a time
            const unsigned long long* p = sf + j2 * (N_RES / 8) + c0;
            unsigned long long vv[8];
            #pragma unroll
            for (int i = 0; i < 8; ++i)
                vv[i] = __hip_atomic_load(p + i, __ATOMIC_RELAXED, __HIP_MEMORY_SCOPE_AGENT);
            for (;;) {
                unsigned mn = 0xffffffffu;
                #pragma unroll
                for (int i = 0; i < 8; ++i) {
                    const unsigned tg = (unsigned)(vv[i] >> 32);
                    mn = (tg < mn) ? tg : mn;
                }
                if (mn >= need) break;
                __builtin_amdgcn_s_sleep(1);
                #pragma unroll
                for (int i = 0; i < 8; ++i)
                    if ((unsigned)(vv[i] >> 32) < need)
                        vv[i] = __hip_atomic_load(p + i, __ATOMIC_RELAXED, __HIP_MEMORY_SCOPE_AGENT);
            }
            #pragma unroll
            for (int i = 0; i < 8; ++i) {
                const float s = __uint_as_float((unsigned)(vv[i] & 0xffffffffu));
                acc = fmaf(out_w[r2 * N_RES + j2 * (N_RES / 8) + c0 + i], s, acc);
            }
        }
        #pragma unroll
        for (int m = 1; m < 8; m <<= 1) acc += __shfl_xor(acc, m, 64);
        if (j2 == 0) d_out[r2] = acc + out_b[r2];
    }
}

extern "C" void kernel_launch(void* const* d_in, const int* in_sizes, int n_in,
                              void* d_out, int out_size, void* d_ws, size_t ws_size,
                              hipStream_t stream) {
    const float* inputs  = (const float*)d_in[0];
    const float* outputs = (const float*)d_in[1];
    const float* w       = (const float*)d_in[2];
    const float* w_in    = (const float*)d_in[3];
    const float* w_feedb = (const float*)d_in[4];
    const float* out_w   = (const float*)d_in[5];
    const float* out_b   = (const float*)d_in[6];
    const float* noise_u = (const float*)d_in[7];
    unsigned long long* slots = (unsigned long long*)d_ws; // 2 x 2048 x 8B = 32 KB

    // re-init tags every call (d_ws is not re-poisoned between graph replays)
    esn_init<<<(2 * N_RES + NTHR - 1) / NTHR, NTHR, 0, stream>>>(slots);
    esn_run<<<NBLK, NTHR, 0, stream>>>(inputs, outputs, w, w_in, w_feedb,
                                       out_w, out_b, noise_u,
                                       (float*)d_out, slots);
}

// Round 10
// 17763.910 us; speedup vs baseline: 1.0019x; 1.0019x over previous
//
#include <hip/hip_runtime.h>

// ESN forward, teacher-forced: s[t] = tanh(w@s[t-1] + w_in@in[t] + w_fb@out[t-1]) + 1e-3*(nu[t]-0.5)
// Persistent kernel, 256 blocks x 256 threads, 8 rows/block, W in LDS (64KB).
//
// Round-9: R5 base + PRODUCER-ALIGNED ownership. Evidence: R8 proved extra
// fabric legs cost ~+1900cy/step (ack+read legs) while op-count reduction
// 250x bought nothing => R5's tag-fused one-way store->poll is leg-optimal;
// the residual stall is detect STRUCTURE. Change: thread tid owns cols
// 8*tid..8*tid+7 = exactly the 64B line block tid publishes. Each thread
// waits on ONE producer (all-or-nothing line detect, published by a single
// 8-lane wave store) instead of max-of-8; producer skew is absorbed across
// threads (fast threads FMA while straggler threads wait) and paid once at
// the reduce barrier. Side effect: per-line pollers 2048 -> 256.
//
// Kept from R5 (8.09ms best): W in LDS [rr][i][tid][j] 16B-lane-stride
// (0 bank conflicts), pre-poll ds_read prefetch + asm fence (lgkm rides out
// the poll's vmcnt), {fp32,tag} fused 8B agent-scope words double-buffered
// by parity, one barrier/step, wave-0 finalize + single-line publish,
// fast tanh (exp2+rcp), s_sleep(1) pacing (skipped on first retry).

#define N_RES   2048
#define N_IN    64
#define N_OUT   32
#define T_STEPS 4096
#define NOISEC  0.001f
#define NBLK    256
#define NTHR    256
#define RPB     8     // rows per block
#define CPT     8     // state words per thread: cols 8*tid .. 8*tid+7

typedef float f32x4 __attribute__((ext_vector_type(4)));

__device__ __forceinline__ float fast_tanh(float x) {
    const float e = __builtin_amdgcn_exp2f(2.8853900818f * x);
    return fmaf(-2.f, __builtin_amdgcn_rcpf(e + 1.f), 1.f);
}

__global__ void esn_init(unsigned long long* __restrict__ slots) {
    const int i = blockIdx.x * blockDim.x + threadIdx.x;
    if (i < 2 * N_RES)
        __hip_atomic_store(slots + i, 0ull, __ATOMIC_RELAXED, __HIP_MEMORY_SCOPE_AGENT);
}

__global__ __launch_bounds__(NTHR, 1)
void esn_run(const float* __restrict__ inputs,    // T x 64
             const float* __restrict__ outputs,   // T x 32
             const float* __restrict__ w,         // 2048 x 2048
             const float* __restrict__ w_in,      // 2048 x 64
             const float* __restrict__ w_feedb,   // 2048 x 32
             const float* __restrict__ out_w,     // 32 x 2048
             const float* __restrict__ out_b,     // 32
             const float* __restrict__ noise_u,   // T x 2048
             float* __restrict__ d_out,           // 32 + 2048
             unsigned long long* __restrict__ slots) { // 2 x 2048 tagged words
    const int tid  = threadIdx.x;
    const int blk  = blockIdx.x;
    const int row0 = blk * RPB;
    const int wav  = tid >> 6;
    const int lan  = tid & 63;

    // [rr][i][tid][j]: element (row = rr*4+j, col = 8*tid+i). 64KB.
    // Per-step read: thread tid -> 16 x ds_read_b128, lane stride 16B
    // (2-way bank aliasing = free). Identical addressing to R5; only the
    // global-side column mapping changed (one-time staging is uncoalesced).
    __shared__ float wlds[2 * 8 * NTHR * 4];
    __shared__ float red[2][4][RPB];

    // ---- one-time: stage W (8 rows x cols 8*tid..8*tid+7 per thread) ----
    #pragma unroll
    for (int r = 0; r < RPB; ++r)
        #pragma unroll
        for (int i = 0; i < CPT; ++i) {
            const float v = w[(size_t)(row0 + r) * N_RES + 8 * tid + i];
            wlds[(((r >> 2) * 8 + i) * NTHR + tid) * 4 + (r & 3)] = v;
        }
    // w_in / w_feedb: one virtual column per thread (tid<96)
    float wex[RPB];
    #pragma unroll
    for (int r = 0; r < RPB; ++r) {
        float v = 0.f;
        if (tid < N_IN)              v = w_in[(row0 + r) * N_IN + tid];
        else if (tid < N_IN + N_OUT) v = w_feedb[(row0 + r) * N_OUT + (tid - N_IN)];
        wex[r] = v;
    }
    __syncthreads();

    for (int t = 1; t < T_STEPS; ++t) {
        const unsigned need = (unsigned)(t - 1);
        // my single 64B line: the output of producer block `tid`
        const unsigned long long* sl =
            slots + (size_t)((t - 1) & 1) * N_RES + tid * CPT;

        // ---- issue poll sweep 0 immediately (earliest vmcnt start) ----
        unsigned long long vv[CPT];
        #pragma unroll
        for (int i = 0; i < CPT; ++i)
            vv[i] = __hip_atomic_load(sl + i, __ATOMIC_RELAXED, __HIP_MEMORY_SCOPE_AGENT);

        // off-critical-path operands (overlap with poll latency)
        float xv = 0.f;
        if (tid < N_IN)              xv = inputs[t * N_IN + tid];
        else if (tid < N_IN + N_OUT) xv = outputs[(t - 1) * N_OUT + (tid - N_IN)];
        float nu = 0.f;
        if (tid < RPB) nu = noise_u[(size_t)t * N_RES + row0 + tid];

        // ---- prefetch W fragment from LDS (state-independent) ----
        f32x4 wv[16];
        #pragma unroll
        for (int rr = 0; rr < 2; ++rr)
            #pragma unroll
            for (int i = 0; i < CPT; ++i)
                wv[rr * 8 + i] = *reinterpret_cast<const f32x4*>(
                    &wlds[((rr * 8 + i) * NTHR + tid) * 4]);

        // fence: nothing above may sink below (ds_reads ride out the poll on
        // the independent lgkmcnt counter)
        asm volatile("" ::: "memory");

        // ---- all-or-nothing detect of MY producer's line ----
        int tries = 0;
        for (;;) {
            unsigned mn = 0xffffffffu;
            #pragma unroll
            for (int i = 0; i < CPT; ++i) {
                const unsigned tg = (unsigned)(vv[i] >> 32);
                mn = (tg < mn) ? tg : mn;
            }
            if (mn >= need) break;
            if (++tries > 1) __builtin_amdgcn_s_sleep(1);
            #pragma unroll
            for (int i = 0; i < CPT; ++i)
                vv[i] = __hip_atomic_load(sl + i, __ATOMIC_RELAXED, __HIP_MEMORY_SCOPE_AGENT);
        }

        // ---- partial dots: 8 rows x my 8 contiguous cols ----
        float acc[RPB];
        #pragma unroll
        for (int r = 0; r < RPB; ++r) acc[r] = 0.f;
        #pragma unroll
        for (int i = 0; i < CPT; ++i) {
            const float sv = __uint_as_float((unsigned)(vv[i] & 0xffffffffu));
            #pragma unroll
            for (int rr = 0; rr < 2; ++rr)
                #pragma unroll
                for (int j = 0; j < 4; ++j)
                    acc[rr * 4 + j] = fmaf(wv[rr * 8 + i][j], sv, acc[rr * 4 + j]);
        }
        #pragma unroll
        for (int r = 0; r < RPB; ++r) acc[r] = fmaf(wex[r], xv, acc[r]);

        // ---- wave reduce: halving exchange (1,2,4) then butterfly (8,16,32) ----
        {   const bool s = (lan & 1);
            #pragma unroll
            for (int r = 0; r < 4; ++r) {
                const float send = s ? acc[r] : acc[r + 4];
                const float got  = __shfl_xor(send, 1, 64);
                acc[r] = (s ? acc[r + 4] : acc[r]) + got;
            }
        }
        {   const bool s = (lan >> 1) & 1;
            #pragma unroll
            for (int r = 0; r < 2; ++r) {
                const float send = s ? acc[r] : acc[r + 2];
                const float got  = __shfl_xor(send, 2, 64);
                acc[r] = (s ? acc[r + 2] : acc[r]) + got;
            }
        }
        {   const bool s = (lan >> 2) & 1;
            const float send = s ? acc[0] : acc[1];
            const float got  = __shfl_xor(send, 4, 64);
            acc[0] = (s ? acc[1] : acc[0]) + got;
        }
        #pragma unroll
        for (int m = 8; m < 64; m <<= 1) acc[0] += __shfl_xor(acc[0], m, 64);
        if (lan < 8) {
            const int rb = 4 * (lan & 1) + 2 * ((lan >> 1) & 1) + ((lan >> 2) & 1);
            red[t & 1][wav][rb] = acc[0];
        }
        __syncthreads();

        // ---- wave 0, lanes 0-7: final sum + tanh + single-line publish ----
        if (tid < RPB) {
            const float tot = red[t & 1][0][tid] + red[t & 1][1][tid]
                            + red[t & 1][2][tid] + red[t & 1][3][tid];
            const float val = fast_tanh(tot) + NOISEC * (nu - 0.5f);
            const unsigned long long pk =
                ((unsigned long long)(unsigned)t << 32) |
                (unsigned long long)__float_as_uint(val);
            __hip_atomic_store(slots + (size_t)(t & 1) * N_RES + row0 + tid, pk,
                               __ATOMIC_RELAXED, __HIP_MEMORY_SCOPE_AGENT);
            if (t == T_STEPS - 1) d_out[32 + row0 + tid] = val;
        }
        // no second barrier: red[] double-buffered by t&1; the next write to
        // this parity is behind the t+1 barrier, after wave0's read.
    }

    // ---- epilogue: block 0 computes readout = out_w @ s_final + out_b ----
    if (blk == 0) {
        const unsigned long long* sf = slots + (size_t)((T_STEPS - 1) & 1) * N_RES;
        const int r2 = tid >> 3, j2 = tid & 7;     // 32 rows x 8 lanes
        const unsigned need = (unsigned)(T_STEPS - 1);
        float acc = 0.f;
        for (int c0 = 0; c0 < N_RES / 8; c0 += 8) { // 256 cols/lane, 8 at a time
            const unsigned long long* p = sf + j2 * (N_RES / 8) + c0;
            unsigned long long vv[8];
            #pragma unroll
            for (int i = 0; i < 8; ++i)
                vv[i] = __hip_atomic_load(p + i, __ATOMIC_RELAXED, __HIP_MEMORY_SCOPE_AGENT);
            for (;;) {
                unsigned mn = 0xffffffffu;
                #pragma unroll
                for (int i = 0; i < 8; ++i) {
                    const unsigned tg = (unsigned)(vv[i] >> 32);
                    mn = (tg < mn) ? tg : mn;
                }
                if (mn >= need) break;
                __builtin_amdgcn_s_sleep(1);
                #pragma unroll
                for (int i = 0; i < 8; ++i)
                    if ((unsigned)(vv[i] >> 32) < need)
                        vv[i] = __hip_atomic_load(p + i, __ATOMIC_RELAXED, __HIP_MEMORY_SCOPE_AGENT);
            }
            #pragma unroll
            for (int i = 0; i < 8; ++i) {
                const float s = __uint_as_float((unsigned)(vv[i] & 0xffffffffu));
                acc = fmaf(out_w[r2 * N_RES + j2 * (N_RES / 8) + c0 + i], s, acc);
            }
        }
        #pragma unroll
        for (int m = 1; m < 8; m <<= 1) acc += __shfl_xor(acc, m, 64);
        if (j2 == 0) d_out[r2] = acc + out_b[r2];
    }
}

extern "C" void kernel_launch(void* const* d_in, const int* in_sizes, int n_in,
                              void* d_out, int out_size, void* d_ws, size_t ws_size,
                              hipStream_t stream) {
    const float* inputs  = (const float*)d_in[0];
    const float* outputs = (const float*)d_in[1];
    const float* w       = (const float*)d_in[2];
    const float* w_in    = (const float*)d_in[3];
    const float* w_feedb = (const float*)d_in[4];
    const float* out_w   = (const float*)d_in[5];
    const float* out_b   = (const float*)d_in[6];
    const float* noise_u = (const float*)d_in[7];
    unsigned long long* slots = (unsigned long long*)d_ws; // 2 x 2048 x 8B = 32 KB

    // re-init tags every call (d_ws is not re-poisoned between graph replays)
    esn_init<<<(2 * N_RES + NTHR - 1) / NTHR, NTHR, 0, stream>>>(slots);
    esn_run<<<NBLK, NTHR, 0, stream>>>(inputs, outputs, w, w_in, w_feedb,
                                       out_w, out_b, noise_u,
                                       (float*)d_out, slots);
}

// Round 11
// 7929.263 us; speedup vs baseline: 2.2445x; 2.2403x over previous
//
#include <hip/hip_runtime.h>

// ESN forward, teacher-forced: s[t] = tanh(w@s[t-1] + w_in@in[t] + w_fb@out[t-1]) + 1e-3*(nu[t]-0.5)
// Persistent kernel, 256 blocks x 256 threads, 8 rows/block, W in LDS (64KB).
//
// Round-10: R5 (8.09ms, best) byte-identical EXCEPT the detect loop: PACED
// POLLING. Evidence synthesis R2-R9: R5 is leg-minimal (R8 +2 legs = +1900cy),
// coalesced strided polls are mandatory (R9 uncoalesced = 2.2x dur), and op-
// rate increases are punished ~linearly (R7 3x rate = +75%). R5 itself burns
// ~6-7 speculative sweeps/step (~65K line-requests/sweep chip-wide) queueing
// at the IC coherence banks -- inflating the RTT and store-visibility it
// waits on. This round: skip the hopeless window with one s_sleep(24)
// (~1536cy, below any plausible step floor), then sweep at s_sleep(2)
// (128cy) cadence, reloading only stale words. Sweeps/step ~6-7 -> ~2-3.
// Asymmetric payoff: if congestion-elastic -> -20-30%; if not, sleep hides
// inside the wait, cost ~0.
//
// Kept from R5: W in LDS [rr][i][tid][j] 16B-lane-stride (0 bank conflicts),
// pre-poll ds_read prefetch + asm fence (lgkm rides out the poll's vmcnt),
// {fp32,tag} fused 8B agent-scope words double-buffered by parity, strided
// column ownership (coalesced polls), one barrier/step, wave-0 finalize +
// single-line publish, fast tanh (exp2+rcp).

#define N_RES   2048
#define N_IN    64
#define N_OUT   32
#define T_STEPS 4096
#define NOISEC  0.001f
#define NBLK    256
#define NTHR    256
#define RPB     8     // rows per block
#define CPT     8     // state words (cols) per thread, stride NTHR

typedef float f32x4 __attribute__((ext_vector_type(4)));

__device__ __forceinline__ float fast_tanh(float x) {
    const float e = __builtin_amdgcn_exp2f(2.8853900818f * x);
    return fmaf(-2.f, __builtin_amdgcn_rcpf(e + 1.f), 1.f);
}

__global__ void esn_init(unsigned long long* __restrict__ slots) {
    const int i = blockIdx.x * blockDim.x + threadIdx.x;
    if (i < 2 * N_RES)
        __hip_atomic_store(slots + i, 0ull, __ATOMIC_RELAXED, __HIP_MEMORY_SCOPE_AGENT);
}

__global__ __launch_bounds__(NTHR, 1)
void esn_run(const float* __restrict__ inputs,    // T x 64
             const float* __restrict__ outputs,   // T x 32
             const float* __restrict__ w,         // 2048 x 2048
             const float* __restrict__ w_in,      // 2048 x 64
             const float* __restrict__ w_feedb,   // 2048 x 32
             const float* __restrict__ out_w,     // 32 x 2048
             const float* __restrict__ out_b,     // 32
             const float* __restrict__ noise_u,   // T x 2048
             float* __restrict__ d_out,           // 32 + 2048
             unsigned long long* __restrict__ slots) { // 2 x 2048 tagged words
    const int tid  = threadIdx.x;
    const int blk  = blockIdx.x;
    const int row0 = blk * RPB;
    const int wav  = tid >> 6;
    const int lan  = tid & 63;

    // [rr][cc][tid][j]: element (row = rr*4+j, col = cc*256+tid). 64KB.
    __shared__ float wlds[2 * 8 * NTHR * 4];
    __shared__ float red[2][4][RPB];

    // ---- one-time: stage my block's 8 W rows into LDS (coalesced reads) ----
    #pragma unroll
    for (int r = 0; r < RPB; ++r)
        #pragma unroll
        for (int cc = 0; cc < 8; ++cc) {
            const float v = w[(size_t)(row0 + r) * N_RES + cc * NTHR + tid];
            wlds[(((r >> 2) * 8 + cc) * NTHR + tid) * 4 + (r & 3)] = v;
        }
    // w_in / w_feedb: one virtual column per thread (tid<96)
    float wex[RPB];
    #pragma unroll
    for (int r = 0; r < RPB; ++r) {
        float v = 0.f;
        if (tid < N_IN)              v = w_in[(row0 + r) * N_IN + tid];
        else if (tid < N_IN + N_OUT) v = w_feedb[(row0 + r) * N_OUT + (tid - N_IN)];
        wex[r] = v;
    }
    __syncthreads();

    for (int t = 1; t < T_STEPS; ++t) {
        const unsigned need = (unsigned)(t - 1);
        const unsigned long long* sl = slots + (size_t)((t - 1) & 1) * N_RES + tid;

        // ---- prefetch W fragment from LDS (state-independent) ----
        f32x4 wv[16];
        #pragma unroll
        for (int rr = 0; rr < 2; ++rr)
            #pragma unroll
            for (int cc = 0; cc < 8; ++cc)
                wv[rr * 8 + cc] = *reinterpret_cast<const f32x4*>(
                    &wlds[((rr * 8 + cc) * NTHR + tid) * 4]);

        // off-critical-path operands (come back during the paced sleep)
        float xv = 0.f;
        if (tid < N_IN)              xv = inputs[t * N_IN + tid];
        else if (tid < N_IN + N_OUT) xv = outputs[(t - 1) * N_OUT + (tid - N_IN)];
        float nu = 0.f;
        if (tid < RPB) nu = noise_u[(size_t)t * N_RES + row0 + tid];

        // fence: nothing above may sink below (ds_reads ride out the poll on
        // the independent lgkmcnt counter)
        asm volatile("" ::: "memory");

        // ---- PACED detect: skip the hopeless window, then sparse sweeps ----
        if (t > 1) __builtin_amdgcn_s_sleep(24);   // ~1536 cy, off critical path
        unsigned long long vv[CPT];
        #pragma unroll
        for (int i = 0; i < CPT; ++i)
            vv[i] = __hip_atomic_load(sl + i * NTHR, __ATOMIC_RELAXED, __HIP_MEMORY_SCOPE_AGENT);
        for (;;) {
            unsigned mn = 0xffffffffu;
            #pragma unroll
            for (int i = 0; i < CPT; ++i) {
                const unsigned tg = (unsigned)(vv[i] >> 32);
                mn = (tg < mn) ? tg : mn;
            }
            if (mn >= need) break;
            __builtin_amdgcn_s_sleep(2);           // 128 cy cadence
            #pragma unroll
            for (int i = 0; i < CPT; ++i)
                if ((unsigned)(vv[i] >> 32) < need)
                    vv[i] = __hip_atomic_load(sl + i * NTHR, __ATOMIC_RELAXED, __HIP_MEMORY_SCOPE_AGENT);
        }

        // ---- partial dots: 8 rows x my 8 strided cols, W from registers ----
        float acc[RPB];
        #pragma unroll
        for (int r = 0; r < RPB; ++r) acc[r] = 0.f;
        #pragma unroll
        for (int i = 0; i < CPT; ++i) {
            const float sv = __uint_as_float((unsigned)(vv[i] & 0xffffffffu));
            #pragma unroll
            for (int rr = 0; rr < 2; ++rr)
                #pragma unroll
                for (int j = 0; j < 4; ++j)
                    acc[rr * 4 + j] = fmaf(wv[rr * 8 + i][j], sv, acc[rr * 4 + j]);
        }
        #pragma unroll
        for (int r = 0; r < RPB; ++r) acc[r] = fmaf(wex[r], xv, acc[r]);

        // ---- wave reduce: halving exchange (1,2,4) then butterfly (8,16,32) ----
        {   const bool s = (lan & 1);
            #pragma unroll
            for (int r = 0; r < 4; ++r) {
                const float send = s ? acc[r] : acc[r + 4];
                const float got  = __shfl_xor(send, 1, 64);
                acc[r] = (s ? acc[r + 4] : acc[r]) + got;
            }
        }
        {   const bool s = (lan >> 1) & 1;
            #pragma unroll
            for (int r = 0; r < 2; ++r) {
                const float send = s ? acc[r] : acc[r + 2];
                const float got  = __shfl_xor(send, 2, 64);
                acc[r] = (s ? acc[r + 2] : acc[r]) + got;
            }
        }
        {   const bool s = (lan >> 2) & 1;
            const float send = s ? acc[0] : acc[1];
            const float got  = __shfl_xor(send, 4, 64);
            acc[0] = (s ? acc[1] : acc[0]) + got;
        }
        #pragma unroll
        for (int m = 8; m < 64; m <<= 1) acc[0] += __shfl_xor(acc[0], m, 64);
        if (lan < 8) {
            const int rb = 4 * (lan & 1) + 2 * ((lan >> 1) & 1) + ((lan >> 2) & 1);
            red[t & 1][wav][rb] = acc[0];
        }
        __syncthreads();

        // ---- wave 0, lanes 0-7: final sum + tanh + single-line publish ----
        if (tid < RPB) {
            const float tot = red[t & 1][0][tid] + red[t & 1][1][tid]
                            + red[t & 1][2][tid] + red[t & 1][3][tid];
            const float val = fast_tanh(tot) + NOISEC * (nu - 0.5f);
            const unsigned long long pk =
                ((unsigned long long)(unsigned)t << 32) |
                (unsigned long long)__float_as_uint(val);
            __hip_atomic_store(slots + (size_t)(t & 1) * N_RES + row0 + tid, pk,
                               __ATOMIC_RELAXED, __HIP_MEMORY_SCOPE_AGENT);
            if (t == T_STEPS - 1) d_out[32 + row0 + tid] = val;
        }
        // no second barrier: red[] double-buffered by t&1; the next write to
        // this parity is behind the t+1 barrier, after wave0's read.
    }

    // ---- epilogue: block 0 computes readout = out_w @ s_final + out_b ----
    if (blk == 0) {
        const unsigned long long* sf = slots + (size_t)((T_STEPS - 1) & 1) * N_RES;
        const int r2 = tid >> 3, j2 = tid & 7;     // 32 rows x 8 lanes
        const unsigned need = (unsigned)(T_STEPS - 1);
        float acc = 0.f;
        for (int c0 = 0; c0 < N_RES / 8; c0 += 8) { // 256 cols/lane, 8 at a time
            const unsigned long long* p = sf + j2 * (N_RES / 8) + c0;
            unsigned long long vv[8];
            #pragma unroll
            for (int i = 0; i < 8; ++i)
                vv[i] = __hip_atomic_load(p + i, __ATOMIC_RELAXED, __HIP_MEMORY_SCOPE_AGENT);
            for (;;) {
                unsigned mn = 0xffffffffu;
                #pragma unroll
                for (int i = 0; i < 8; ++i) {
                    const unsigned tg = (unsigned)(vv[i] >> 32);
                    mn = (tg < mn) ? tg : mn;
                }
                if (mn >= need) break;
                __builtin_amdgcn_s_sleep(1);
                #pragma unroll
                for (int i = 0; i < 8; ++i)
                    if ((unsigned)(vv[i] >> 32) < need)
                        vv[i] = __hip_atomic_load(p + i, __ATOMIC_RELAXED, __HIP_MEMORY_SCOPE_AGENT);
            }
            #pragma unroll
            for (int i = 0; i < 8; ++i) {
                const float s = __uint_as_float((unsigned)(vv[i] & 0xffffffffu));
                acc = fmaf(out_w[r2 * N_RES + j2 * (N_RES / 8) + c0 + i], s, acc);
            }
        }
        #pragma unroll
        for (int m = 1; m < 8; m <<= 1) acc += __shfl_xor(acc, m, 64);
        if (j2 == 0) d_out[r2] = acc + out_b[r2];
    }
}

extern "C" void kernel_launch(void* const* d_in, const int* in_sizes, int n_in,
                              void* d_out, int out_size, void* d_ws, size_t ws_size,
                              hipStream_t stream) {
    const float* inputs  = (const float*)d_in[0];
    const float* outputs = (const float*)d_in[1];
    const float* w       = (const float*)d_in[2];
    const float* w_in    = (const float*)d_in[3];
    const float* w_feedb = (const float*)d_in[4];
    const float* out_w   = (const float*)d_in[5];
    const float* out_b   = (const float*)d_in[6];
    const float* noise_u = (const float*)d_in[7];
    unsigned long long* slots = (unsigned long long*)d_ws; // 2 x 2048 x 8B = 32 KB

    // re-init tags every call (d_ws is not re-poisoned between graph replays)
    esn_init<<<(2 * N_RES + NTHR - 1) / NTHR, NTHR, 0, stream>>>(slots);
    esn_run<<<NBLK, NTHR, 0, stream>>>(inputs, outputs, w, w_in, w_feedb,
                                       out_w, out_b, noise_u,
                                       (float*)d_out, slots);
}

// Round 12
// 7900.188 us; speedup vs baseline: 2.2528x; 1.0037x over previous
//
#include <hip/hip_runtime.h>

// ESN forward, teacher-forced: s[t] = tanh(w@s[t-1] + w_in@in[t] + w_fb@out[t-1]) + 1e-3*(nu[t]-0.5)
// Persistent kernel, 256 blocks x 256 threads, 8 rows/block, W in LDS (64KB).
//
// Round-11: R10 + 16B COHERENT POLL LOADS (halve poll op count, zero new legs).
// Thread owns 4 column PAIRS {2tid, 2tid+1} + 512*i; one global_load_dwordx4
// sc1 (agent-coherent, gfx940+ encoding of agent-scope load) returns TWO
// {data,tag} words. Tags are per-word so freshness semantics are unchanged;
// aligned 8B halves cannot tear. Wave coalescing improves to 1KB/instr.
// Poll cadence tightened to s_sleep(1) (64cy) now that sweeps cost half.
//
// Evidence so far: R10 measured congestion down-elasticity ~nil (FETCH -25%,
// dur -2%) => serial-latency floor ~4650cy/step = visibility + poll RTT +
// detect quantum + compute tail + producer skew. R8: +2 legs = +1900cy.
// R9: uncoalesced = 2.2x. R7: 3x op rate = +75%. This round is the last
// zero-risk op-count lever; if <3% it confirms the floor.
//
// Kept from R10: W in LDS [rr][k][tid][j] 16B-lane-stride (0 bank conflicts),
// pre-poll ds_read prefetch + asm fence, {fp32,tag} fused words double-
// buffered by parity, initial s_sleep(24) hopeless-window skip, one barrier
// per step, wave-0 finalize + single-line publish, fast tanh (exp2+rcp).

#define N_RES   2048
#define N_IN    64
#define N_OUT   32
#define T_STEPS 4096
#define NOISEC  0.001f
#define NBLK    256
#define NTHR    256
#define RPB     8     // rows per block
#define CPT     8     // state words per thread: pairs {2tid,2tid+1}+512i

typedef float f32x4 __attribute__((ext_vector_type(4)));
typedef unsigned int u32x4 __attribute__((ext_vector_type(4)));

__device__ __forceinline__ float fast_tanh(float x) {
    const float e = __builtin_amdgcn_exp2f(2.8853900818f * x);
    return fmaf(-2.f, __builtin_amdgcn_rcpf(e + 1.f), 1.f);
}

// 4 x 16B agent-coherent loads (2 tagged words each), one vmcnt drain.
// Single asm block: no reorder hazard between load and waitcnt (rule #18).
__device__ __forceinline__ void poll4(const unsigned long long* b,
                                      u32x4& q0, u32x4& q1, u32x4& q2, u32x4& q3) {
    asm volatile(
        "global_load_dwordx4 %0, %4, off sc1\n\t"
        "global_load_dwordx4 %1, %5, off sc1\n\t"
        "global_load_dwordx4 %2, %6, off sc1\n\t"
        "global_load_dwordx4 %3, %7, off sc1\n\t"
        "s_waitcnt vmcnt(0)"
        : "=&v"(q0), "=&v"(q1), "=&v"(q2), "=&v"(q3)
        : "v"(b), "v"(b + 512), "v"(b + 1024), "v"(b + 1536)
        : "memory");
}

__global__ void esn_init(unsigned long long* __restrict__ slots) {
    const int i = blockIdx.x * blockDim.x + threadIdx.x;
    if (i < 2 * N_RES)
        __hip_atomic_store(slots + i, 0ull, __ATOMIC_RELAXED, __HIP_MEMORY_SCOPE_AGENT);
}

__global__ __launch_bounds__(NTHR, 1)
void esn_run(const float* __restrict__ inputs,    // T x 64
             const float* __restrict__ outputs,   // T x 32
             const float* __restrict__ w,         // 2048 x 2048
             const float* __restrict__ w_in,      // 2048 x 64
             const float* __restrict__ w_feedb,   // 2048 x 32
             const float* __restrict__ out_w,     // 32 x 2048
             const float* __restrict__ out_b,     // 32
             const float* __restrict__ noise_u,   // T x 2048
             float* __restrict__ d_out,           // 32 + 2048
             unsigned long long* __restrict__ slots) { // 2 x 2048 tagged words
    const int tid  = threadIdx.x;
    const int blk  = blockIdx.x;
    const int row0 = blk * RPB;
    const int wav  = tid >> 6;
    const int lan  = tid & 63;

    // [rr][k][tid][j]: element (row = rr*4+j, col = 512*(k>>1) + 2*tid + (k&1)). 64KB.
    __shared__ float wlds[2 * 8 * NTHR * 4];
    __shared__ float red[2][4][RPB];

    // ---- one-time: stage my block's 8 W rows into LDS ----
    #pragma unroll
    for (int r = 0; r < RPB; ++r)
        #pragma unroll
        for (int k = 0; k < CPT; ++k) {
            const int col = 512 * (k >> 1) + 2 * tid + (k & 1);
            wlds[(((r >> 2) * 8 + k) * NTHR + tid) * 4 + (r & 3)] =
                w[(size_t)(row0 + r) * N_RES + col];
        }
    // w_in / w_feedb: one virtual column per thread (tid<96)
    float wex[RPB];
    #pragma unroll
    for (int r = 0; r < RPB; ++r) {
        float v = 0.f;
        if (tid < N_IN)              v = w_in[(row0 + r) * N_IN + tid];
        else if (tid < N_IN + N_OUT) v = w_feedb[(row0 + r) * N_OUT + (tid - N_IN)];
        wex[r] = v;
    }
    __syncthreads();

    for (int t = 1; t < T_STEPS; ++t) {
        const unsigned need = (unsigned)(t - 1);
        const unsigned long long* sl =
            slots + (size_t)((t - 1) & 1) * N_RES + 2 * tid;

        // ---- prefetch W fragment from LDS (state-independent) ----
        f32x4 wv[16];
        #pragma unroll
        for (int rr = 0; rr < 2; ++rr)
            #pragma unroll
            for (int k = 0; k < CPT; ++k)
                wv[rr * 8 + k] = *reinterpret_cast<const f32x4*>(
                    &wlds[((rr * 8 + k) * NTHR + tid) * 4]);

        // off-critical-path operands (return during the paced sleep)
        float xv = 0.f;
        if (tid < N_IN)              xv = inputs[t * N_IN + tid];
        else if (tid < N_IN + N_OUT) xv = outputs[(t - 1) * N_OUT + (tid - N_IN)];
        float nu = 0.f;
        if (tid < RPB) nu = noise_u[(size_t)t * N_RES + row0 + tid];

        // fence: nothing above may sink below (lgkm rides out the poll's vmcnt)
        asm volatile("" ::: "memory");

        // ---- PACED detect: skip hopeless window, then 16B-paired sweeps ----
        if (t > 1) __builtin_amdgcn_s_sleep(24);   // ~1536 cy, off critical path
        u32x4 q0, q1, q2, q3;                       // {data0,tag0,data1,tag1}
        poll4(sl, q0, q1, q2, q3);
        for (;;) {
            unsigned mn = q0.y; 
            mn = (q0.w < mn) ? q0.w : mn;
            mn = (q1.y < mn) ? q1.y : mn;  mn = (q1.w < mn) ? q1.w : mn;
            mn = (q2.y < mn) ? q2.y : mn;  mn = (q2.w < mn) ? q2.w : mn;
            mn = (q3.y < mn) ? q3.y : mn;  mn = (q3.w < mn) ? q3.w : mn;
            if (mn >= need) break;
            __builtin_amdgcn_s_sleep(1);           // 64 cy cadence
            poll4(sl, q0, q1, q2, q3);
        }
        float sv[CPT];
        sv[0] = __uint_as_float(q0.x);  sv[1] = __uint_as_float(q0.z);
        sv[2] = __uint_as_float(q1.x);  sv[3] = __uint_as_float(q1.z);
        sv[4] = __uint_as_float(q2.x);  sv[5] = __uint_as_float(q2.z);
        sv[6] = __uint_as_float(q3.x);  sv[7] = __uint_as_float(q3.z);

        // ---- partial dots: 8 rows x my 8 cols, W from registers ----
        float acc[RPB];
        #pragma unroll
        for (int r = 0; r < RPB; ++r) acc[r] = 0.f;
        #pragma unroll
        for (int k = 0; k < CPT; ++k) {
            #pragma unroll
            for (int rr = 0; rr < 2; ++rr)
                #pragma unroll
                for (int j = 0; j < 4; ++j)
                    acc[rr * 4 + j] = fmaf(wv[rr * 8 + k][j], sv[k], acc[rr * 4 + j]);
        }
        #pragma unroll
        for (int r = 0; r < RPB; ++r) acc[r] = fmaf(wex[r], xv, acc[r]);

        // ---- wave reduce: halving exchange (1,2,4) then butterfly (8,16,32) ----
        {   const bool s = (lan & 1);
            #pragma unroll
            for (int r = 0; r < 4; ++r) {
                const float send = s ? acc[r] : acc[r + 4];
                const float got  = __shfl_xor(send, 1, 64);
                acc[r] = (s ? acc[r + 4] : acc[r]) + got;
            }
        }
        {   const bool s = (lan >> 1) & 1;
            #pragma unroll
            for (int r = 0; r < 2; ++r) {
                const float send = s ? acc[r] : acc[r + 2];
                const float got  = __shfl_xor(send, 2, 64);
                acc[r] = (s ? acc[r + 2] : acc[r]) + got;
            }
        }
        {   const bool s = (lan >> 2) & 1;
            const float send = s ? acc[0] : acc[1];
            const float got  = __shfl_xor(send, 4, 64);
            acc[0] = (s ? acc[1] : acc[0]) + got;
        }
        #pragma unroll
        for (int m = 8; m < 64; m <<= 1) acc[0] += __shfl_xor(acc[0], m, 64);
        if (lan < 8) {
            const int rb = 4 * (lan & 1) + 2 * ((lan >> 1) & 1) + ((lan >> 2) & 1);
            red[t & 1][wav][rb] = acc[0];
        }
        __syncthreads();

        // ---- wave 0, lanes 0-7: final sum + tanh + single-line publish ----
        if (tid < RPB) {
            const float tot = red[t & 1][0][tid] + red[t & 1][1][tid]
                            + red[t & 1][2][tid] + red[t & 1][3][tid];
            const float val = fast_tanh(tot) + NOISEC * (nu - 0.5f);
            const unsigned long long pk =
                ((unsigned long long)(unsigned)t << 32) |
                (unsigned long long)__float_as_uint(val);
            __hip_atomic_store(slots + (size_t)(t & 1) * N_RES + row0 + tid, pk,
                               __ATOMIC_RELAXED, __HIP_MEMORY_SCOPE_AGENT);
            if (t == T_STEPS - 1) d_out[32 + row0 + tid] = val;
        }
        // no second barrier: red[] double-buffered by t&1; the next write to
        // this parity is behind the t+1 barrier, after wave0's read.
    }

    // ---- epilogue: block 0 computes readout = out_w @ s_final + out_b ----
    if (blk == 0) {
        const unsigned long long* sf = slots + (size_t)((T_STEPS - 1) & 1) * N_RES;
        const int r2 = tid >> 3, j2 = tid & 7;     // 32 rows x 8 lanes
        const unsigned need = (unsigned)(T_STEPS - 1);
        float acc = 0.f;
        for (int c0 = 0; c0 < N_RES / 8; c0 += 8) { // 256 cols/lane, 8 at a time
            const unsigned long long* p = sf + j2 * (N_RES / 8) + c0;
            unsigned long long vv[8];
            #pragma unroll
            for (int i = 0; i < 8; ++i)
                vv[i] = __hip_atomic_load(p + i, __ATOMIC_RELAXED, __HIP_MEMORY_SCOPE_AGENT);
            for (;;) {
                unsigned mn = 0xffffffffu;
                #pragma unroll
                for (int i = 0; i < 8; ++i) {
                    const unsigned tg = (unsigned)(vv[i] >> 32);
                    mn = (tg < mn) ? tg : mn;
                }
                if (mn >= need) break;
                __builtin_amdgcn_s_sleep(1);
                #pragma unroll
                for (int i = 0; i < 8; ++i)
                    if ((unsigned)(vv[i] >> 32) < need)
                        vv[i] = __hip_atomic_load(p + i, __ATOMIC_RELAXED, __HIP_MEMORY_SCOPE_AGENT);
            }
            #pragma unroll
            for (int i = 0; i < 8; ++i) {
                const float s = __uint_as_float((unsigned)(vv[i] & 0xffffffffu));
                acc = fmaf(out_w[r2 * N_RES + j2 * (N_RES / 8) + c0 + i], s, acc);
            }
        }
        #pragma unroll
        for (int m = 1; m < 8; m <<= 1) acc += __shfl_xor(acc, m, 64);
        if (j2 == 0) d_out[r2] = acc + out_b[r2];
    }
}

extern "C" void kernel_launch(void* const* d_in, const int* in_sizes, int n_in,
                              void* d_out, int out_size, void* d_ws, size_t ws_size,
                              hipStream_t stream) {
    const float* inputs  = (const float*)d_in[0];
    const float* outputs = (const float*)d_in[1];
    const float* w       = (const float*)d_in[2];
    const float* w_in    = (const float*)d_in[3];
    const float* w_feedb = (const float*)d_in[4];
    const float* out_w   = (const float*)d_in[5];
    const float* out_b   = (const float*)d_in[6];
    const float* noise_u = (const float*)d_in[7];
    unsigned long long* slots = (unsigned long long*)d_ws; // 2 x 2048 x 8B = 32 KB

    // re-init tags every call (d_ws is not re-poisoned between graph replays)
    esn_init<<<(2 * N_RES + NTHR - 1) / NTHR, NTHR, 0, stream>>>(slots);
    esn_run<<<NBLK, NTHR, 0, stream>>>(inputs, outputs, w, w_in, w_feedb,
                                       out_w, out_b, noise_u,
                                       (float*)d_out, slots);
}